// Round 14
// baseline (250.327 us; speedup 1.0000x reference)
//
#include <hip/hip_runtime.h>
#include <stdint.h>
#include <stddef.h>

// CapsuleFC: B=64, N_IN=2048, D_IN=16, N_OUT=64, D_OUT=16
constexpr int B_ = 64, N_ = 2048, A_ = 16, M_ = 64, D_ = 16;
constexpr float SCALE_ = 0.25f;   // 1/sqrt(16)
constexpr float EPS_ = 1e-6f;

typedef float f32x4 __attribute__((ext_vector_type(4)));

__device__ __forceinline__ float rdlane(float v, int l) {
  return __uint_as_float(__builtin_amdgcn_readlane(__float_as_uint(v), l));
}

// grid: 4*nch blocks (nch=256 -> 1024). block: 256 threads = 4 waves;
// wave wv owns 4 batches (b0 = bg*16 + wv*4); lane l owns out-capsule m=l.
//
// R14 PIVOT: NO LDS, NO BARRIERS. R8-R13 proved the staged-LDS family is
// pinned at 8 lockstep waves/CU (allocator pairs ~VGPR_Count AGPRs with every
// build: resident waves = 512/(2*VGPR) per SIMD) and every barrier exposes
// stage latency; all schedule variants landed 177-254us. Key layout fact:
// w[n][a][m][d] is ALREADY coalesced for direct consumption — lane m reads
// w[n][a][m][0..15] = 64B contiguous; a wave reads 4KB/a-plane contiguous.
// So load wr straight from L2 into registers (4x dwordx4 per a), zero
// staging. Waves run free; per-wave vmcnt pipelining hides L2 latency.
// XCD co-location: all 16 b-quad sharers of chunk ch on one XCD; chunk w
// slab = C*64KB = 512KB fits the 4MB XCD L2 -> w read from HBM once.
__global__ __launch_bounds__(256, 2)
void caps_main(
    const float* __restrict__ input,   // [B,N,A]
    const float* __restrict__ cact,    // [B,N]
    const float* __restrict__ ncv,     // [B,M,D]
    const float* __restrict__ nact,    // [B,M]
    const float* __restrict__ w,       // [N,A,M,D]
    float* __restrict__ qk_out,        // [B,N,M]
    float* __restrict__ partial,       // [nch,B,M,D]
    int C, int nch)
{
  const int tid  = threadIdx.x;
  const int lane = tid & 63;
  const int wv   = __builtin_amdgcn_readfirstlane(tid >> 6);

  // co-XCD mapping: the 4 bgroup-sharers of chunk ch land on xcd = flat&7
  const int flat = blockIdx.x;
  int bg, ch;
  if (nch & 7) { bg = flat & 3; ch = flat >> 2; }
  else { bg = (flat >> 3) & 3; ch = ((flat >> 5) << 3) | (flat & 7); }

  const int b0 = bg * 16 + wv * 4;
  const int n0 = ch * C;

  // per-lane input/cact carriers (R13, verified):
  //   icur: lane l holds input[b0 + (l>>4)][n][l&15]
  //   cacur: lane l holds cact[b0 + (l&3)][n]
  const int ib_row = b0 + (lane >> 4);
  const int ia_col = lane & 15;
  const int cb_row = b0 + (lane & 3);

  // loop-invariant per-(b,m) values in registers
  float na[4], cv[4][16];
#pragma unroll
  for (int bi = 0; bi < 4; ++bi) {
    na[bi] = nact[(b0 + bi) * M_ + lane];
    const f32x4* np4 = (const f32x4*)(ncv + ((size_t)(b0 + bi) * M_ + lane) * D_);
#pragma unroll
    for (int j = 0; j < 4; ++j) {
      const f32x4 t = np4[j];
      cv[bi][4*j+0] = t.x; cv[bi][4*j+1] = t.y;
      cv[bi][4*j+2] = t.z; cv[bi][4*j+3] = t.w;
    }
  }

  float acc[4][16];
#pragma unroll
  for (int bi = 0; bi < 4; ++bi)
#pragma unroll
    for (int d = 0; d < 16; ++d) acc[bi][d] = 0.f;

  // prologue prefetch for n0
  float icur  = input[(size_t)(ib_row * N_ + n0) * A_ + ia_col];
  float cacur = cact[(size_t)cb_row * N_ + n0];

  for (int k = 0; k < C; ++k) {
    const int n  = n0 + k;
    const int nn = (k + 1 < C) ? (n + 1) : n;   // OOB guard on last iter

    // prefetch next-n input/cact (independent; retire under this n's loads)
    float inext  = input[(size_t)(ib_row * N_ + nn) * A_ + ia_col];
    float canext = cact[(size_t)cb_row * N_ + nn];

    float v[4][16];
#pragma unroll
    for (int bi = 0; bi < 4; ++bi)
#pragma unroll
      for (int d = 0; d < 16; ++d) v[bi][d] = 0.f;

    // ---- votes: wr straight from L2, per a-plane (coalesced 4KB/wave)
    const float* wn = w + ((size_t)n << 14);   // n*A*M*D floats
#pragma unroll
    for (int a = 0; a < 16; ++a) {
      const f32x4* wp = (const f32x4*)(wn + (size_t)(a * (M_ * D_)) + lane * D_);
      f32x4 wr0 = wp[0], wr1 = wp[1], wr2 = wp[2], wr3 = wp[3];
#pragma unroll
      for (int bi = 0; bi < 4; ++bi) {
        const float x = rdlane(icur, bi * 16 + a);
        v[bi][0]  += x * wr0.x; v[bi][1]  += x * wr0.y;
        v[bi][2]  += x * wr0.z; v[bi][3]  += x * wr0.w;
        v[bi][4]  += x * wr1.x; v[bi][5]  += x * wr1.y;
        v[bi][6]  += x * wr1.z; v[bi][7]  += x * wr1.w;
        v[bi][8]  += x * wr2.x; v[bi][9]  += x * wr2.y;
        v[bi][10] += x * wr2.z; v[bi][11] += x * wr2.w;
        v[bi][12] += x * wr3.x; v[bi][13] += x * wr3.y;
        v[bi][14] += x * wr3.z; v[bi][15] += x * wr3.w;
      }
    }

    // ---- scores -> wave-local softmax (m = lane) -> qk -> accumulate
#pragma unroll
    for (int bi = 0; bi < 4; ++bi) {
      float s = 0.f;
#pragma unroll
      for (int d = 0; d < 16; ++d) s += v[bi][d] * cv[bi][d];
      s *= SCALE_;
      // |s| small (~N(0,0.2)); max-subtraction cancels in the ratio -> skip
      const float e = __expf(s);
      const float ena = e * na[bi];
      float Ps = ena;
#pragma unroll
      for (int off = 32; off >= 1; off >>= 1) Ps += __shfl_xor(Ps, off, 64);
      const float qk = ena / Ps;   // 1e-10 terms ~2e-10 relative: dropped
      qk_out[((size_t)(b0 + bi) * N_ + n) * M_ + lane] = qk;
      float ab = rdlane(cacur, bi);
      ab = fminf(fmaxf(ab, EPS_), 1.0f - EPS_);
      const float wq = qk * ab;
#pragma unroll
      for (int d = 0; d < 16; ++d) acc[bi][d] += wq * v[bi][d];
    }

    icur  = inext;
    cacur = canext;
  }

  // partial[ch][b][m][d]
#pragma unroll
  for (int bi = 0; bi < 4; ++bi) {
    float* pp = partial + (((size_t)ch * B_ + (b0 + bi)) * M_ + lane) * D_;
#pragma unroll
    for (int j = 0; j < 4; ++j) {
      f32x4 t;
      t.x = acc[bi][4*j+0]; t.y = acc[bi][4*j+1];
      t.z = acc[bi][4*j+2]; t.w = acc[bi][4*j+3];
      __builtin_nontemporal_store(t, (f32x4*)pp + j);
    }
  }
}

__global__ void caps_reduce(const float* __restrict__ part,
                            const float* __restrict__ nain,
                            float* __restrict__ out, int nch)
{
  const int i = blockIdx.x * 256 + threadIdx.x;  // one thread per out[b,m,d]
  float s = 0.f;
  for (int c = 0; c < nch; ++c) s += part[(size_t)c * (B_ * M_ * D_) + i];
  out[i] = s;
  if (i < B_ * M_) out[B_ * M_ * D_ + i] = nain[i];  // next_act passthrough
}

extern "C" void kernel_launch(void* const* d_in, const int* in_sizes, int n_in,
                              void* d_out, int out_size, void* d_ws, size_t ws_size,
                              hipStream_t stream)
{
  const float* input = (const float*)d_in[0];
  const float* cact  = (const float*)d_in[1];
  const float* ncv   = (const float*)d_in[2];
  const float* nact  = (const float*)d_in[3];
  const float* w     = (const float*)d_in[4];

  float* out     = (float*)d_out;
  float* qk_out  = out + (B_ * M_ * D_) + (B_ * M_);   // after out and next_act
  float* partial = (float*)d_ws;

  // nch=256 -> grid 1024; needs 67MB ws; degrade if smaller
  int nch = 256;
  while ((size_t)nch * (size_t)(B_ * M_ * D_) * sizeof(float) > ws_size && nch > 32) nch >>= 1;
  const int C = N_ / nch;

  hipLaunchKernelGGL(caps_main, dim3(4 * nch), dim3(256), 0, stream,
                     input, cact, ncv, nact, w, qk_out, partial, C, nch);
  hipLaunchKernelGGL(caps_reduce, dim3(B_ * M_ * D_ / 256), dim3(256), 0, stream,
                     partial, nact, out, nch);
}